// Round 8
// baseline (438.662 us; speedup 1.0000x reference)
//
#include <hip/hip_runtime.h>
#include <math.h>

#define SEQ   2048
#define BATCH 4
#define DIM   1024
#define NHEAD 16
#define HD    64
#define NQKV  3072   // 3*DIM
#define MROWS (BATCH*SEQ)   // 8192
#define GK    1024   // GEMM K
#define QKP   2048   // q,k packed pitch (v stored transposed separately)

typedef __attribute__((ext_vector_type(8))) short bf16x8;
typedef __attribute__((ext_vector_type(4))) float f32x4;
typedef __attribute__((ext_vector_type(4))) unsigned int u32x4;
typedef unsigned int u32;

// q-scale: (1/sqrt(64)) * log2(e)
#define QSCALE 0.18033688011112042f
#define INV2PI 0.15915494309189535f
#define TWOPI  6.283185307179586f

#if __has_builtin(__builtin_amdgcn_exp2f)
#define EXP2(x) __builtin_amdgcn_exp2f(x)
#else
#define EXP2(x) exp2f(x)
#endif

__device__ inline unsigned short f2bf(float f) {
    unsigned u = __builtin_bit_cast(unsigned, f);
    u += 0x7fff + ((u >> 16) & 1);      // round-to-nearest-even
    return (unsigned short)(u >> 16);
}
__device__ inline float bf2f(unsigned short h) {
    unsigned u = ((unsigned)h) << 16;
    return __builtin_bit_cast(float, u);
}
__device__ inline void split2(float v, unsigned short& h, unsigned short& l) {
    h = f2bf(v);
    l = f2bf(v - bf2f(h));
}
__device__ inline void gl_lds16(const void* g, void* l) {
    __builtin_amdgcn_global_load_lds(
        (const __attribute__((address_space(1))) unsigned int*)g,
        (__attribute__((address_space(3))) unsigned int*)l, 16, 0, 0);
}

// ---------------------------------------------------------------------------
// Kernel 1: prep = split_x + split_wT merged.
// ---------------------------------------------------------------------------
__global__ __launch_bounds__(256) void prep(const float* __restrict__ X,
                                            const float* __restrict__ W,
                                            unsigned short* __restrict__ Xh,
                                            unsigned short* __restrict__ Xl,
                                            unsigned short* __restrict__ WhT,
                                            unsigned short* __restrict__ WlT)
{
    __shared__ unsigned short Th[32 * 36];
    __shared__ unsigned short Tl[32 * 36];
    const int bx = blockIdx.x;
    const int tid = threadIdx.x;

    if (bx < 4096) {
        size_t base = ((size_t)bx * 256 + tid) * 8;
        float4 a = *reinterpret_cast<const float4*>(&X[base]);
        float4 b = *reinterpret_cast<const float4*>(&X[base + 4]);
        float v[8] = {a.x, a.y, a.z, a.w, b.x, b.y, b.z, b.w};
        unsigned short h[8], l[8];
#pragma unroll
        for (int j = 0; j < 8; ++j) split2(v[j], h[j], l[j]);
        *reinterpret_cast<bf16x8*>(&Xh[base]) = *reinterpret_cast<bf16x8*>(h);
        *reinterpret_cast<bf16x8*>(&Xl[base]) = *reinterpret_cast<bf16x8*>(l);
        return;
    }

    const int b2 = bx - 4096;
    const int n0 = (b2 % 96) * 32;
    const int k0 = (b2 / 96) * 32;
    {
        int kr = tid >> 3;
        int nc = (tid & 7) * 4;
        float4 v = *reinterpret_cast<const float4*>(&W[(size_t)(k0 + kr) * NQKV + n0 + nc]);
        float vv[4] = {v.x, v.y, v.z, v.w};
#pragma unroll
        for (int j = 0; j < 4; ++j) {
            unsigned short h, l;
            split2(vv[j], h, l);
            Th[kr * 36 + nc + j] = h;
            Tl[kr * 36 + nc + j] = l;
        }
    }
    __syncthreads();
    {
        int nl = tid >> 3;
        int kc = (tid & 7) * 4;
        ushort4 h, l;
        h.x = Th[(kc + 0) * 36 + nl]; l.x = Tl[(kc + 0) * 36 + nl];
        h.y = Th[(kc + 1) * 36 + nl]; l.y = Tl[(kc + 1) * 36 + nl];
        h.z = Th[(kc + 2) * 36 + nl]; l.z = Tl[(kc + 2) * 36 + nl];
        h.w = Th[(kc + 3) * 36 + nl]; l.w = Tl[(kc + 3) * 36 + nl];
        size_t o = (size_t)(n0 + nl) * GK + k0 + kc;
        *reinterpret_cast<ushort4*>(&WhT[o]) = h;
        *reinterpret_cast<ushort4*>(&WlT[o]) = l;
    }
}

// ---------------------------------------------------------------------------
// Kernel 2: split-bf16 MFMA GEMM, BK=64 single-buffer 2-barrier K-loop
// (R5-proven structure), fused fast-sincos RoPE epilogue.
// ---------------------------------------------------------------------------
__global__ __launch_bounds__(256, 2) void gemm_split(
    const unsigned short* __restrict__ Xh, const unsigned short* __restrict__ Xl,
    const unsigned short* __restrict__ WhT, const unsigned short* __restrict__ WlT,
    const float* __restrict__ bias, unsigned short* __restrict__ qkB,
    unsigned short* __restrict__ VTo)
{
    __shared__ __align__(16) unsigned short lds[4 * 128 * 64];
    unsigned short* Ah = lds;
    unsigned short* Al = lds + 128 * 64;
    unsigned short* Bh = lds + 2 * 128 * 64;
    unsigned short* Bl = lds + 3 * 128 * 64;

    const int tid  = threadIdx.x;
    const int w    = tid >> 6;
    const int lane = tid & 63;
    const int quad = lane >> 4;
    const int l16  = lane & 15;
    const int n0 = blockIdx.x * 128;
    const int m0 = blockIdx.y * 128;
    const int wm = (w >> 1) * 64;
    const int wn = (w & 1) * 64;

    auto stage = [&](const unsigned short* __restrict__ g, unsigned short* l,
                     int row0, int k0) {
#pragma unroll
        for (int p = 0; p < 4; ++p) {
            int i = (p * 4 + w) * 64 + lane;
            int r = i >> 3;
            int s = (i & 7) ^ (r & 7);
            gl_lds16(g + (size_t)(row0 + r) * GK + k0 + s * 8,
                     l + (size_t)(p * 4 + w) * 512);
        }
    };

    f32x4 acc[4][4];
#pragma unroll
    for (int mi = 0; mi < 4; ++mi)
#pragma unroll
        for (int ni = 0; ni < 4; ++ni) acc[mi][ni] = (f32x4){0.f, 0.f, 0.f, 0.f};

    stage(Xh, Ah, m0, 0);
    stage(Xl, Al, m0, 0);
    stage(WhT, Bh, n0, 0);
    stage(WlT, Bl, n0, 0);

    for (int kt = 0; kt < GK / 64; ++kt) {
        __syncthreads();

#pragma unroll
        for (int ks = 0; ks < 2; ++ks) {
            bf16x8 ah[4], al[4], bh[4], bl[4];
            int sp = ((ks * 4 + quad) ^ (l16 & 7)) * 8;
#pragma unroll
            for (int t = 0; t < 4; ++t) {
                int mrow = (wm + t * 16 + l16) * 64;
                ah[t] = *reinterpret_cast<const bf16x8*>(&Ah[mrow + sp]);
                al[t] = *reinterpret_cast<const bf16x8*>(&Al[mrow + sp]);
                int nrow = (wn + t * 16 + l16) * 64;
                bh[t] = *reinterpret_cast<const bf16x8*>(&Bh[nrow + sp]);
                bl[t] = *reinterpret_cast<const bf16x8*>(&Bl[nrow + sp]);
            }
#pragma unroll
            for (int mi = 0; mi < 4; ++mi)
#pragma unroll
                for (int ni = 0; ni < 4; ++ni) {
                    acc[mi][ni] = __builtin_amdgcn_mfma_f32_16x16x32_bf16(
                        al[mi], bh[ni], acc[mi][ni], 0, 0, 0);
                    acc[mi][ni] = __builtin_amdgcn_mfma_f32_16x16x32_bf16(
                        ah[mi], bl[ni], acc[mi][ni], 0, 0, 0);
                    acc[mi][ni] = __builtin_amdgcn_mfma_f32_16x16x32_bf16(
                        ah[mi], bh[ni], acc[mi][ni], 0, 0, 0);
                }
        }

        if (kt < GK / 64 - 1) {
            __syncthreads();
            int k0 = (kt + 1) * 64;
            stage(Xh, Ah, m0, k0);
            stage(Xl, Al, m0, k0);
            stage(WhT, Bh, n0, k0);
            stage(WlT, Bl, n0, k0);
        }
    }

    // ---- epilogue: +bias; q/k: fused RoPE (fast sincos) then bf16 once;
    // v: transposed store ----
#pragma unroll
    for (int ni = 0; ni < 4; ++ni) {
        int n = n0 + wn + ni * 16 + l16;
        float bv = bias[n];
        if (n < 2 * DIM) {
            float scale = (n < DIM) ? QSCALE : 1.0f;
            bool doRope = ((n & 63) < 32);        // uniform per ni
            float invf = 0.f;
            if (doRope) {
                int pair = (n & 31) >> 1;
                invf = exp2f(-(float)pair * (13.287712379549449f / 16.0f)) * INV2PI;
            }
#pragma unroll
            for (int mi = 0; mi < 4; ++mi) {
                int m = m0 + wm + mi * 16 + quad * 4;
#pragma unroll
                for (int r = 0; r < 4; ++r) {
                    float v = acc[mi][ni][r] + bv;
                    float o = v;
                    if (doRope) {
                        float partner = __shfl_xor(v, 1, 64);  // n^1 in lane l16^1
                        int token = (m + r) & (SEQ - 1);
                        float rev = (float)token * invf;
                        rev -= floorf(rev);
                        float ang = rev * TWOPI;
                        float s = __sinf(ang), c = __cosf(ang);
                        o = (n & 1) ? (v * c + partner * s) : (v * c - partner * s);
                    }
                    qkB[(size_t)(m + r) * QKP + n] = f2bf(o * scale);
                }
            }
        } else {
            int d  = n & 63;
            int hh = (n - 2 * DIM) >> 6;
#pragma unroll
            for (int mi = 0; mi < 4; ++mi) {
                int m = m0 + wm + mi * 16 + quad * 4;
                int bhh = (m >> 11) * 16 + hh;
                ushort4 pkv;
                pkv.x = f2bf(acc[mi][ni][0] + bv);
                pkv.y = f2bf(acc[mi][ni][1] + bv);
                pkv.z = f2bf(acc[mi][ni][2] + bv);
                pkv.w = f2bf(acc[mi][ni][3] + bv);
                *reinterpret_cast<ushort4*>(
                    &VTo[((size_t)bhh * HD + d) * SEQ + (m & (SEQ - 1))]) = pkv;
            }
        }
    }
}

// ---------------------------------------------------------------------------
// Kernel 3: barrier-free MFMA attention, all fragments direct from global.
//  - No LDS, no __syncthreads: per 32-key step each wave loads K-frags
//    (4x dwordx4, key-permuted via per-lane constant row offsets) and
//    V-frags (4x dwordx4, natural order) straight from global. All 4 waves
//    + 4 co-resident blocks (same bh, XCD swizzle) touch the same 8 KB
//    window -> L1/L2 hits.
//  - Frag patterns are 16 rows x 64B contiguous -> fully coalesced.
//  - S^T = mfma(Kfrag, Qfrag); P packed bf16 natural-key-order (permutation
//    folded into K row offsets, R5-verified); l via ones-row MFMA.
// ---------------------------------------------------------------------------
__global__ __launch_bounds__(256, 4) void attn_direct(const unsigned short* __restrict__ qkB,
                                                      const unsigned short* __restrict__ VT,
                                                      float* __restrict__ out)
{
    const int tid  = threadIdx.x;
    const int w    = tid >> 6;
    const int lane = tid & 63;
    const int quad = lane >> 4;
    const int l16  = lane & 15;
    const int bh  = blockIdx.x;       // 64  -> XCD = bh % 8
    const int qtb = blockIdx.y;       // 16
    const int bi = bh >> 4, h = bh & 15;
    const int m0 = qtb * 128 + w * 32;

    const unsigned short* Qg  = qkB + (size_t)bi * SEQ * QKP + h * HD;
    const unsigned short* Kg  = Qg + DIM;
    const unsigned short* VTg = VT + (size_t)bh * HD * SEQ;

    // Q fragments (held in registers for the whole key sweep)
    bf16x8 qf[2][2];
#pragma unroll
    for (int qt = 0; qt < 2; ++qt)
#pragma unroll
        for (int ks = 0; ks < 2; ++ks)
            qf[qt][ks] = *reinterpret_cast<const bf16x8*>(
                &Qg[(size_t)(m0 + qt * 16 + l16) * QKP + ks * 32 + quad * 8]);

    // per-lane permuted key row offsets: a(v)=((v>>2)&3)*8+((v>>4)&1)*4+(v&3)
    const int ka0 = ((l16 >> 2) & 3) * 8 + (l16 & 3);   // t=0 rows
    const int ka1 = ka0 + 4;                            // t=1 rows

    // ones-row A-operand: C row 0 = column sums of B
    const u32 onepair = (l16 == 0) ? 0x3F803F80u : 0u;
    const bf16x8 ones_a = __builtin_bit_cast(
        bf16x8, (u32x4){onepair, onepair, onepair, onepair});

    f32x4 y[2][4];
#pragma unroll
    for (int qt = 0; qt < 2; ++qt)
#pragma unroll
        for (int dt = 0; dt < 4; ++dt) y[qt][dt] = (f32x4){0.f, 0.f, 0.f, 0.f};
    f32x4 yl[2] = {(f32x4){0.f, 0.f, 0.f, 0.f}, (f32x4){0.f, 0.f, 0.f, 0.f}};

#pragma unroll 2
    for (int c0 = 0; c0 < SEQ; c0 += 32) {
        // ---- issue all loads for this 32-key window ----
        bf16x8 kb[2][2], vb[4];
#pragma unroll
        for (int ks = 0; ks < 2; ++ks) {
            kb[0][ks] = *reinterpret_cast<const bf16x8*>(
                &Kg[(size_t)(c0 + ka0) * QKP + ks * 32 + quad * 8]);
            kb[1][ks] = *reinterpret_cast<const bf16x8*>(
                &Kg[(size_t)(c0 + ka1) * QKP + ks * 32 + quad * 8]);
        }
#pragma unroll
        for (int dt = 0; dt < 4; ++dt)
            vb[dt] = *reinterpret_cast<const bf16x8*>(
                &VTg[(size_t)(dt * 16 + l16) * SEQ + c0 + quad * 8]);

        // ---- S^T, exp, pack ----
        u32 pk[2][2][2];
#pragma unroll
        for (int t = 0; t < 2; ++t)
#pragma unroll
            for (int qt = 0; qt < 2; ++qt) {
                f32x4 st = __builtin_amdgcn_mfma_f32_16x16x32_bf16(
                    kb[t][0], qf[qt][0], (f32x4){0.f, 0.f, 0.f, 0.f}, 0, 0, 0);
                st = __builtin_amdgcn_mfma_f32_16x16x32_bf16(
                    kb[t][1], qf[qt][1], st, 0, 0, 0);
                u32 e[4];
#pragma unroll
                for (int r = 0; r < 4; ++r)
                    e[r] = __builtin_bit_cast(u32, EXP2(st[r]));
                pk[qt][t][0] = __builtin_amdgcn_perm(e[1], e[0], 0x07060302u);
                pk[qt][t][1] = __builtin_amdgcn_perm(e[3], e[2], 0x07060302u);
            }

        bf16x8 pfragq[2];
#pragma unroll
        for (int qt = 0; qt < 2; ++qt) {
            pfragq[qt] = __builtin_bit_cast(
                bf16x8, (u32x4){pk[qt][0][0], pk[qt][0][1], pk[qt][1][0], pk[qt][1][1]});
            yl[qt] = __builtin_amdgcn_mfma_f32_16x16x32_bf16(
                ones_a, pfragq[qt], yl[qt], 0, 0, 0);
        }
        // ---- PV ----
#pragma unroll
        for (int dt = 0; dt < 4; ++dt)
#pragma unroll
            for (int qt = 0; qt < 2; ++qt)
                y[qt][dt] = __builtin_amdgcn_mfma_f32_16x16x32_bf16(
                    vb[dt], pfragq[qt], y[qt][dt], 0, 0, 0);
    }

    // ---- final: broadcast l from C row 0, normalize, store ----
    float rsv[2];
#pragma unroll
    for (int qt = 0; qt < 2; ++qt) {
        float lv = __shfl(yl[qt][0], l16, 64);
        rsv[qt] = 1.f / lv;
    }

#pragma unroll
    for (int qt = 0; qt < 2; ++qt) {
        int token = m0 + qt * 16 + l16;
        size_t obase = ((size_t)(bi * SEQ + token)) * DIM + h * HD;
#pragma unroll
        for (int dt = 0; dt < 4; ++dt) {
            float4 o;
            o.x = y[qt][dt][0] * rsv[qt];
            o.y = y[qt][dt][1] * rsv[qt];
            o.z = y[qt][dt][2] * rsv[qt];
            o.w = y[qt][dt][3] * rsv[qt];
            *reinterpret_cast<float4*>(&out[obase + dt * 16 + quad * 4]) = o;
        }
    }
}

// ---------------------------------------------------------------------------
extern "C" void kernel_launch(void* const* d_in, const int* in_sizes, int n_in,
                              void* d_out, int out_size, void* d_ws, size_t ws_size,
                              hipStream_t stream)
{
    const float* x    = (const float*)d_in[0];
    const float* W    = (const float*)d_in[1];
    const float* bias = (const float*)d_in[2];
    float* out = (float*)d_out;

    unsigned short* qkB = (unsigned short*)d_ws;                  // 8192*2048
    unsigned short* VT  = qkB + (size_t)MROWS * QKP;              // 64*64*2048
    unsigned short* Xh  = VT + (size_t)BATCH * NHEAD * HD * SEQ;  // 8192*1024
    unsigned short* Xl  = Xh + (size_t)MROWS * GK;
    unsigned short* WhT = Xl + (size_t)MROWS * GK;                // 3072*1024
    unsigned short* WlT = WhT + (size_t)NQKV * GK;

    prep<<<4096 + 3072, 256, 0, stream>>>(x, W, Xh, Xl, WhT, WlT);
    gemm_split<<<dim3(NQKV / 128, MROWS / 128), 256, 0, stream>>>(Xh, Xl, WhT, WlT, bias, qkB, VT);
    attn_direct<<<dim3(BATCH * NHEAD, SEQ / 128), 256, 0, stream>>>(qkB, VT, out);
}

// Round 9
// 289.103 us; speedup vs baseline: 1.5173x; 1.5173x over previous
//
#include <hip/hip_runtime.h>
#include <math.h>

#define SEQ   2048
#define BATCH 4
#define DIM   1024
#define NHEAD 16
#define HD    64
#define NQKV  3072   // 3*DIM
#define MROWS (BATCH*SEQ)   // 8192
#define GK    1024   // GEMM K
#define QKP   2048   // q,k packed pitch (v stored transposed separately)

typedef __attribute__((ext_vector_type(8))) short bf16x8;
typedef __attribute__((ext_vector_type(4))) float f32x4;
typedef __attribute__((ext_vector_type(4))) unsigned int u32x4;
typedef unsigned int u32;

// q-scale: (1/sqrt(64)) * log2(e)
#define QSCALE 0.18033688011112042f
#define INV2PI 0.15915494309189535f
#define TWOPI  6.283185307179586f

#if __has_builtin(__builtin_amdgcn_exp2f)
#define EXP2(x) __builtin_amdgcn_exp2f(x)
#else
#define EXP2(x) exp2f(x)
#endif

__device__ inline unsigned short f2bf(float f) {
    unsigned u = __builtin_bit_cast(unsigned, f);
    u += 0x7fff + ((u >> 16) & 1);      // round-to-nearest-even
    return (unsigned short)(u >> 16);
}
__device__ inline float bf2f(unsigned short h) {
    unsigned u = ((unsigned)h) << 16;
    return __builtin_bit_cast(float, u);
}
__device__ inline void split2(float v, unsigned short& h, unsigned short& l) {
    h = f2bf(v);
    l = f2bf(v - bf2f(h));
}
__device__ inline void gl_lds16(const void* g, void* l) {
    __builtin_amdgcn_global_load_lds(
        (const __attribute__((address_space(1))) unsigned int*)g,
        (__attribute__((address_space(3))) unsigned int*)l, 16, 0, 0);
}

// ---------------------------------------------------------------------------
// Kernel 1: prep = split_x + split_wT merged.
// ---------------------------------------------------------------------------
__global__ __launch_bounds__(256) void prep(const float* __restrict__ X,
                                            const float* __restrict__ W,
                                            unsigned short* __restrict__ Xh,
                                            unsigned short* __restrict__ Xl,
                                            unsigned short* __restrict__ WhT,
                                            unsigned short* __restrict__ WlT)
{
    __shared__ unsigned short Th[32 * 36];
    __shared__ unsigned short Tl[32 * 36];
    const int bx = blockIdx.x;
    const int tid = threadIdx.x;

    if (bx < 4096) {
        size_t base = ((size_t)bx * 256 + tid) * 8;
        float4 a = *reinterpret_cast<const float4*>(&X[base]);
        float4 b = *reinterpret_cast<const float4*>(&X[base + 4]);
        float v[8] = {a.x, a.y, a.z, a.w, b.x, b.y, b.z, b.w};
        unsigned short h[8], l[8];
#pragma unroll
        for (int j = 0; j < 8; ++j) split2(v[j], h[j], l[j]);
        *reinterpret_cast<bf16x8*>(&Xh[base]) = *reinterpret_cast<bf16x8*>(h);
        *reinterpret_cast<bf16x8*>(&Xl[base]) = *reinterpret_cast<bf16x8*>(l);
        return;
    }

    const int b2 = bx - 4096;
    const int n0 = (b2 % 96) * 32;
    const int k0 = (b2 / 96) * 32;
    {
        int kr = tid >> 3;
        int nc = (tid & 7) * 4;
        float4 v = *reinterpret_cast<const float4*>(&W[(size_t)(k0 + kr) * NQKV + n0 + nc]);
        float vv[4] = {v.x, v.y, v.z, v.w};
#pragma unroll
        for (int j = 0; j < 4; ++j) {
            unsigned short h, l;
            split2(vv[j], h, l);
            Th[kr * 36 + nc + j] = h;
            Tl[kr * 36 + nc + j] = l;
        }
    }
    __syncthreads();
    {
        int nl = tid >> 3;
        int kc = (tid & 7) * 4;
        ushort4 h, l;
        h.x = Th[(kc + 0) * 36 + nl]; l.x = Tl[(kc + 0) * 36 + nl];
        h.y = Th[(kc + 1) * 36 + nl]; l.y = Tl[(kc + 1) * 36 + nl];
        h.z = Th[(kc + 2) * 36 + nl]; l.z = Tl[(kc + 2) * 36 + nl];
        h.w = Th[(kc + 3) * 36 + nl]; l.w = Tl[(kc + 3) * 36 + nl];
        size_t o = (size_t)(n0 + nl) * GK + k0 + kc;
        *reinterpret_cast<ushort4*>(&WhT[o]) = h;
        *reinterpret_cast<ushort4*>(&WlT[o]) = l;
    }
}

// ---------------------------------------------------------------------------
// Kernel 2: split-bf16 MFMA GEMM, BK=64 single-buffer 2-barrier K-loop
// (R5-proven structure), fused fast-sincos RoPE epilogue.
// ---------------------------------------------------------------------------
__global__ __launch_bounds__(256, 2) void gemm_split(
    const unsigned short* __restrict__ Xh, const unsigned short* __restrict__ Xl,
    const unsigned short* __restrict__ WhT, const unsigned short* __restrict__ WlT,
    const float* __restrict__ bias, unsigned short* __restrict__ qkB,
    unsigned short* __restrict__ VTo)
{
    __shared__ __align__(16) unsigned short lds[4 * 128 * 64];
    unsigned short* Ah = lds;
    unsigned short* Al = lds + 128 * 64;
    unsigned short* Bh = lds + 2 * 128 * 64;
    unsigned short* Bl = lds + 3 * 128 * 64;

    const int tid  = threadIdx.x;
    const int w    = tid >> 6;
    const int lane = tid & 63;
    const int quad = lane >> 4;
    const int l16  = lane & 15;
    const int n0 = blockIdx.x * 128;
    const int m0 = blockIdx.y * 128;
    const int wm = (w >> 1) * 64;
    const int wn = (w & 1) * 64;

    auto stage = [&](const unsigned short* __restrict__ g, unsigned short* l,
                     int row0, int k0) {
#pragma unroll
        for (int p = 0; p < 4; ++p) {
            int i = (p * 4 + w) * 64 + lane;
            int r = i >> 3;
            int s = (i & 7) ^ (r & 7);
            gl_lds16(g + (size_t)(row0 + r) * GK + k0 + s * 8,
                     l + (size_t)(p * 4 + w) * 512);
        }
    };

    f32x4 acc[4][4];
#pragma unroll
    for (int mi = 0; mi < 4; ++mi)
#pragma unroll
        for (int ni = 0; ni < 4; ++ni) acc[mi][ni] = (f32x4){0.f, 0.f, 0.f, 0.f};

    stage(Xh, Ah, m0, 0);
    stage(Xl, Al, m0, 0);
    stage(WhT, Bh, n0, 0);
    stage(WlT, Bl, n0, 0);

    for (int kt = 0; kt < GK / 64; ++kt) {
        __syncthreads();

#pragma unroll
        for (int ks = 0; ks < 2; ++ks) {
            bf16x8 ah[4], al[4], bh[4], bl[4];
            int sp = ((ks * 4 + quad) ^ (l16 & 7)) * 8;
#pragma unroll
            for (int t = 0; t < 4; ++t) {
                int mrow = (wm + t * 16 + l16) * 64;
                ah[t] = *reinterpret_cast<const bf16x8*>(&Ah[mrow + sp]);
                al[t] = *reinterpret_cast<const bf16x8*>(&Al[mrow + sp]);
                int nrow = (wn + t * 16 + l16) * 64;
                bh[t] = *reinterpret_cast<const bf16x8*>(&Bh[nrow + sp]);
                bl[t] = *reinterpret_cast<const bf16x8*>(&Bl[nrow + sp]);
            }
#pragma unroll
            for (int mi = 0; mi < 4; ++mi)
#pragma unroll
                for (int ni = 0; ni < 4; ++ni) {
                    acc[mi][ni] = __builtin_amdgcn_mfma_f32_16x16x32_bf16(
                        al[mi], bh[ni], acc[mi][ni], 0, 0, 0);
                    acc[mi][ni] = __builtin_amdgcn_mfma_f32_16x16x32_bf16(
                        ah[mi], bl[ni], acc[mi][ni], 0, 0, 0);
                    acc[mi][ni] = __builtin_amdgcn_mfma_f32_16x16x32_bf16(
                        ah[mi], bh[ni], acc[mi][ni], 0, 0, 0);
                }
        }

        if (kt < GK / 64 - 1) {
            __syncthreads();
            int k0 = (kt + 1) * 64;
            stage(Xh, Ah, m0, k0);
            stage(Xl, Al, m0, k0);
            stage(WhT, Bh, n0, k0);
            stage(WlT, Bl, n0, k0);
        }
    }

    // ---- epilogue: +bias; q/k: fused RoPE (fast sincos) then bf16 once;
    // v: transposed store ----
#pragma unroll
    for (int ni = 0; ni < 4; ++ni) {
        int n = n0 + wn + ni * 16 + l16;
        float bv = bias[n];
        if (n < 2 * DIM) {
            float scale = (n < DIM) ? QSCALE : 1.0f;
            bool doRope = ((n & 63) < 32);        // uniform per ni
            float invf = 0.f;
            if (doRope) {
                int pair = (n & 31) >> 1;
                invf = exp2f(-(float)pair * (13.287712379549449f / 16.0f)) * INV2PI;
            }
#pragma unroll
            for (int mi = 0; mi < 4; ++mi) {
                int m = m0 + wm + mi * 16 + quad * 4;
#pragma unroll
                for (int r = 0; r < 4; ++r) {
                    float v = acc[mi][ni][r] + bv;
                    float o = v;
                    if (doRope) {
                        float partner = __shfl_xor(v, 1, 64);  // n^1 in lane l16^1
                        int token = (m + r) & (SEQ - 1);
                        float rev = (float)token * invf;
                        rev -= floorf(rev);
                        float ang = rev * TWOPI;
                        float s = __sinf(ang), c = __cosf(ang);
                        o = (n & 1) ? (v * c + partner * s) : (v * c - partner * s);
                    }
                    qkB[(size_t)(m + r) * QKP + n] = f2bf(o * scale);
                }
            }
        } else {
            int d  = n & 63;
            int hh = (n - 2 * DIM) >> 6;
#pragma unroll
            for (int mi = 0; mi < 4; ++mi) {
                int m = m0 + wm + mi * 16 + quad * 4;
                int bhh = (m >> 11) * 16 + hh;
                ushort4 pkv;
                pkv.x = f2bf(acc[mi][ni][0] + bv);
                pkv.y = f2bf(acc[mi][ni][1] + bv);
                pkv.z = f2bf(acc[mi][ni][2] + bv);
                pkv.w = f2bf(acc[mi][ni][3] + bv);
                *reinterpret_cast<ushort4*>(
                    &VTo[((size_t)bhh * HD + d) * SEQ + (m & (SEQ - 1))]) = pkv;
            }
        }
    }
}

// ---------------------------------------------------------------------------
// Kernel 3: MFMA flash attention, S^T form, 256-query blocks (4 qt/wave),
// double-buffered K/V LDS, ONE barrier per 128-key tile.
//  - grid (bh=64, qtb=8): flat%8 = bh%8 -> same-bh blocks on one XCD.
//  - K/V frag reads + staging + barriers amortized over 2x queries vs R6.
//  - loop: sync (buf ready, prior readers done); issue stage(next buf);
//    compute(cur buf) -> loads get a full compute phase to land.
//  - Q frags direct from global (one-time); K staged with in-32 key
//    permutation so packed-P is natural key order; l via ones-row MFMA.
// ---------------------------------------------------------------------------
__global__ __launch_bounds__(256, 2) void attn_mfma4(const unsigned short* __restrict__ qkB,
                                                     const unsigned short* __restrict__ VT,
                                                     float* __restrict__ out)
{
    __shared__ __align__(16) unsigned short Ks[2][128 * 64];
    __shared__ __align__(16) unsigned short Vt[2][64 * 128];

    const int tid  = threadIdx.x;
    const int w    = tid >> 6;
    const int lane = tid & 63;
    const int quad = lane >> 4;
    const int l16  = lane & 15;
    const int bh  = blockIdx.x;       // 64  -> XCD = bh % 8
    const int qtb = blockIdx.y;       // 8
    const int bi = bh >> 4, h = bh & 15;
    const int m0 = qtb * 256 + w * 64;   // this wave's first query

    const unsigned short* Qg  = qkB + (size_t)bi * SEQ * QKP + h * HD;
    const unsigned short* Kg  = Qg + DIM;
    const unsigned short* VTg = VT + (size_t)bh * HD * SEQ;

    // ---- Q fragments direct from global (held for the whole sweep) ----
    bf16x8 qf[4][2];
#pragma unroll
    for (int qt = 0; qt < 4; ++qt)
#pragma unroll
        for (int ks = 0; ks < 2; ++ks)
            qf[qt][ks] = *reinterpret_cast<const bf16x8*>(
                &Qg[(size_t)(m0 + qt * 16 + l16) * QKP + ks * 32 + quad * 8]);

    // stage K (key-permuted) + V^T tile c0 into buffer b
    auto stageKV = [&](int b, int c0) {
#pragma unroll
        for (int p = 0; p < 4; ++p) {
            int seg = p * 4 + w;
            int r = seg * 8 + (lane >> 3);
            int a = (r & ~31) | (((r >> 2) & 3) << 3)
                  | (((r >> 4) & 1) << 2) | (r & 3);
            int s = (lane & 7) ^ (r & 7);
            gl_lds16(Kg + (size_t)(c0 + a) * QKP + s * 8, &Ks[b][seg * 512]);
        }
#pragma unroll
        for (int p = 0; p < 4; ++p) {
            int seg = p * 4 + w;
            int r = seg * 4 + (lane >> 4);
            int s = (lane & 15) ^ (r & 15);
            gl_lds16(VTg + (size_t)r * SEQ + c0 + s * 8, &Vt[b][seg * 512]);
        }
    };

    // ones-row A-operand: C row 0 = column sums of B
    const u32 onepair = (l16 == 0) ? 0x3F803F80u : 0u;
    const bf16x8 ones_a = __builtin_bit_cast(
        bf16x8, (u32x4){onepair, onepair, onepair, onepair});

    f32x4 y[4][4];
#pragma unroll
    for (int qt = 0; qt < 4; ++qt)
#pragma unroll
        for (int dt = 0; dt < 4; ++dt) y[qt][dt] = (f32x4){0.f, 0.f, 0.f, 0.f};
    f32x4 yl[4];
#pragma unroll
    for (int qt = 0; qt < 4; ++qt) yl[qt] = (f32x4){0.f, 0.f, 0.f, 0.f};

    stageKV(0, 0);

    for (int t = 0; t < SEQ / 128; ++t) {
        __syncthreads();   // buf t&1 loads complete; prior readers of other buf done
        const int b = t & 1;
        if (t < SEQ / 128 - 1) stageKV(b ^ 1, (t + 1) * 128);

        const unsigned short* Kb = Ks[b];
        const unsigned short* Vb = Vt[b];

#pragma unroll
        for (int ksp = 0; ksp < 4; ++ksp) {
            u32 pk[4][2][2];   // [qt][t2][half]
#pragma unroll
            for (int t2 = 0; t2 < 2; ++t2) {
                int kt = ksp * 2 + t2;
                int krow = (kt * 16 + l16) * 64;
                bf16x8 kb0 = *reinterpret_cast<const bf16x8*>(
                    &Kb[krow + ((quad ^ (l16 & 7))) * 8]);
                bf16x8 kb1 = *reinterpret_cast<const bf16x8*>(
                    &Kb[krow + (((4 + quad) ^ (l16 & 7))) * 8]);
#pragma unroll
                for (int qt = 0; qt < 4; ++qt) {
                    f32x4 st = __builtin_amdgcn_mfma_f32_16x16x32_bf16(
                        kb0, qf[qt][0], (f32x4){0.f, 0.f, 0.f, 0.f}, 0, 0, 0);
                    st = __builtin_amdgcn_mfma_f32_16x16x32_bf16(
                        kb1, qf[qt][1], st, 0, 0, 0);
                    u32 e[4];
#pragma unroll
                    for (int r = 0; r < 4; ++r)
                        e[r] = __builtin_bit_cast(u32, EXP2(st[r]));
                    pk[qt][t2][0] = __builtin_amdgcn_perm(e[1], e[0], 0x07060302u);
                    pk[qt][t2][1] = __builtin_amdgcn_perm(e[3], e[2], 0x07060302u);
                }
            }
            bf16x8 pfragq[4];
#pragma unroll
            for (int qt = 0; qt < 4; ++qt) {
                pfragq[qt] = __builtin_bit_cast(
                    bf16x8, (u32x4){pk[qt][0][0], pk[qt][0][1], pk[qt][1][0], pk[qt][1][1]});
                yl[qt] = __builtin_amdgcn_mfma_f32_16x16x32_bf16(
                    ones_a, pfragq[qt], yl[qt], 0, 0, 0);
            }
#pragma unroll
            for (int dt = 0; dt < 4; ++dt) {
                int row = dt * 16 + l16;
                bf16x8 vfrag = *reinterpret_cast<const bf16x8*>(
                    &Vb[row * 128 + (((ksp * 4 + quad) ^ l16)) * 8]);
#pragma unroll
                for (int qt = 0; qt < 4; ++qt)
                    y[qt][dt] = __builtin_amdgcn_mfma_f32_16x16x32_bf16(
                        vfrag, pfragq[qt], y[qt][dt], 0, 0, 0);
            }
        }
    }

    // ---- final: broadcast l from C row 0, normalize, store ----
#pragma unroll
    for (int qt = 0; qt < 4; ++qt) {
        float lv = __shfl(yl[qt][0], l16, 64);
        float rsv = 1.f / lv;
        int token = m0 + qt * 16 + l16;
        size_t obase = ((size_t)(bi * SEQ + token)) * DIM + h * HD;
#pragma unroll
        for (int dt = 0; dt < 4; ++dt) {
            float4 o;
            o.x = y[qt][dt][0] * rsv;
            o.y = y[qt][dt][1] * rsv;
            o.z = y[qt][dt][2] * rsv;
            o.w = y[qt][dt][3] * rsv;
            *reinterpret_cast<float4*>(&out[obase + dt * 16 + quad * 4]) = o;
        }
    }
}

// ---------------------------------------------------------------------------
extern "C" void kernel_launch(void* const* d_in, const int* in_sizes, int n_in,
                              void* d_out, int out_size, void* d_ws, size_t ws_size,
                              hipStream_t stream)
{
    const float* x    = (const float*)d_in[0];
    const float* W    = (const float*)d_in[1];
    const float* bias = (const float*)d_in[2];
    float* out = (float*)d_out;

    unsigned short* qkB = (unsigned short*)d_ws;                  // 8192*2048
    unsigned short* VT  = qkB + (size_t)MROWS * QKP;              // 64*64*2048
    unsigned short* Xh  = VT + (size_t)BATCH * NHEAD * HD * SEQ;  // 8192*1024
    unsigned short* Xl  = Xh + (size_t)MROWS * GK;
    unsigned short* WhT = Xl + (size_t)MROWS * GK;                // 3072*1024
    unsigned short* WlT = WhT + (size_t)NQKV * GK;

    prep<<<4096 + 3072, 256, 0, stream>>>(x, W, Xh, Xl, WhT, WlT);
    gemm_split<<<dim3(NQKV / 128, MROWS / 128), 256, 0, stream>>>(Xh, Xl, WhT, WlT, bias, qkB, VT);
    attn_mfma4<<<dim3(BATCH * NHEAD, SEQ / 256), 256, 0, stream>>>(qkB, VT, out);
}

// Round 10
// 224.439 us; speedup vs baseline: 1.9545x; 1.2881x over previous
//
#include <hip/hip_runtime.h>
#include <math.h>

#define SEQ   2048
#define BATCH 4
#define DIM   1024
#define NHEAD 16
#define HD    64
#define NQKV  3072   // 3*DIM
#define MROWS (BATCH*SEQ)   // 8192
#define GK    1024   // GEMM K
#define QKP   2048   // q,k packed pitch (v stored transposed separately)

typedef __attribute__((ext_vector_type(8))) short bf16x8;
typedef __attribute__((ext_vector_type(8))) _Float16 f16x8;
typedef __attribute__((ext_vector_type(4))) float f32x4;
typedef __attribute__((ext_vector_type(4))) unsigned int u32x4;
typedef unsigned int u32;

// q-scale: (1/sqrt(64)) * log2(e)
#define QSCALE 0.18033688011112042f
#define INV2PI 0.15915494309189535f
#define TWOPI  6.283185307179586f

#if __has_builtin(__builtin_amdgcn_exp2f)
#define EXP2(x) __builtin_amdgcn_exp2f(x)
#else
#define EXP2(x) exp2f(x)
#endif

__device__ inline unsigned short f2bf(float f) {
    unsigned u = __builtin_bit_cast(unsigned, f);
    u += 0x7fff + ((u >> 16) & 1);      // round-to-nearest-even
    return (unsigned short)(u >> 16);
}
__device__ inline void gl_lds16(const void* g, void* l) {
    __builtin_amdgcn_global_load_lds(
        (const __attribute__((address_space(1))) unsigned int*)g,
        (__attribute__((address_space(3))) unsigned int*)l, 16, 0, 0);
}

// ---------------------------------------------------------------------------
// Kernel 1: prep — X fp32 -> Xf fp16 [8192][1024]; W fp32 -> WfT fp16
// transposed [3072][1024].
// ---------------------------------------------------------------------------
__global__ __launch_bounds__(256) void prep(const float* __restrict__ X,
                                            const float* __restrict__ W,
                                            unsigned short* __restrict__ Xf,
                                            unsigned short* __restrict__ WfT)
{
    __shared__ unsigned short Th[32 * 36];
    const int bx = blockIdx.x;
    const int tid = threadIdx.x;

    if (bx < 4096) {
        size_t base = ((size_t)bx * 256 + tid) * 8;
        float4 a = *reinterpret_cast<const float4*>(&X[base]);
        float4 b = *reinterpret_cast<const float4*>(&X[base + 4]);
        float v[8] = {a.x, a.y, a.z, a.w, b.x, b.y, b.z, b.w};
        _Float16 h[8];
#pragma unroll
        for (int j = 0; j < 8; ++j) h[j] = (_Float16)v[j];
        *reinterpret_cast<f16x8*>(&Xf[base]) = *reinterpret_cast<f16x8*>(h);
        return;
    }

    const int b2 = bx - 4096;             // 3072 tiles
    const int n0 = (b2 % 96) * 32;
    const int k0 = (b2 / 96) * 32;
    {
        int kr = tid >> 3;
        int nc = (tid & 7) * 4;
        float4 v = *reinterpret_cast<const float4*>(&W[(size_t)(k0 + kr) * NQKV + n0 + nc]);
        float vv[4] = {v.x, v.y, v.z, v.w};
#pragma unroll
        for (int j = 0; j < 4; ++j)
            Th[kr * 36 + nc + j] = __builtin_bit_cast(unsigned short, (_Float16)vv[j]);
    }
    __syncthreads();
    {
        int nl = tid >> 3;
        int kc = (tid & 7) * 4;
        ushort4 h;
        h.x = Th[(kc + 0) * 36 + nl];
        h.y = Th[(kc + 1) * 36 + nl];
        h.z = Th[(kc + 2) * 36 + nl];
        h.w = Th[(kc + 3) * 36 + nl];
        *reinterpret_cast<ushort4*>(&WfT[(size_t)(n0 + nl) * GK + k0 + kc]) = h;
    }
}

// ---------------------------------------------------------------------------
// Kernel 2: single-pass fp16 MFMA GEMM (no hi/lo split — fp16's 11-bit
// mantissa puts GEMM noise 5x below the bf16 output-storage rounding).
// 128x128 tile, BK=64, 2 planes (32 KB LDS), 2-barrier K-loop, 3 blocks/CU.
// Fused fast-sincos RoPE epilogue; q,k -> qkB bf16; v -> VTo transposed bf16.
// ---------------------------------------------------------------------------
__global__ __launch_bounds__(256, 3) void gemm_f16(
    const unsigned short* __restrict__ Xf, const unsigned short* __restrict__ WfT,
    const float* __restrict__ bias, unsigned short* __restrict__ qkB,
    unsigned short* __restrict__ VTo)
{
    __shared__ __align__(16) unsigned short lds[2 * 128 * 64];   // 32 KB
    unsigned short* Af = lds;
    unsigned short* Bf = lds + 128 * 64;

    const int tid  = threadIdx.x;
    const int w    = tid >> 6;
    const int lane = tid & 63;
    const int quad = lane >> 4;
    const int l16  = lane & 15;
    const int n0 = blockIdx.x * 128;
    const int m0 = blockIdx.y * 128;
    const int wm = (w >> 1) * 64;
    const int wn = (w & 1) * 64;

    auto stage = [&](const unsigned short* __restrict__ g, unsigned short* l,
                     int row0, int k0) {
#pragma unroll
        for (int p = 0; p < 4; ++p) {
            int i = (p * 4 + w) * 64 + lane;
            int r = i >> 3;
            int s = (i & 7) ^ (r & 7);
            gl_lds16(g + (size_t)(row0 + r) * GK + k0 + s * 8,
                     l + (size_t)(p * 4 + w) * 512);
        }
    };

    f32x4 acc[4][4];
#pragma unroll
    for (int mi = 0; mi < 4; ++mi)
#pragma unroll
        for (int ni = 0; ni < 4; ++ni) acc[mi][ni] = (f32x4){0.f, 0.f, 0.f, 0.f};

    stage(Xf, Af, m0, 0);
    stage(WfT, Bf, n0, 0);

    for (int kt = 0; kt < GK / 64; ++kt) {
        __syncthreads();

#pragma unroll
        for (int ks = 0; ks < 2; ++ks) {
            f16x8 af[4], bf[4];
            int sp = ((ks * 4 + quad) ^ (l16 & 7)) * 8;
#pragma unroll
            for (int t = 0; t < 4; ++t) {
                af[t] = *reinterpret_cast<const f16x8*>(&Af[(wm + t * 16 + l16) * 64 + sp]);
                bf[t] = *reinterpret_cast<const f16x8*>(&Bf[(wn + t * 16 + l16) * 64 + sp]);
            }
#pragma unroll
            for (int mi = 0; mi < 4; ++mi)
#pragma unroll
                for (int ni = 0; ni < 4; ++ni)
                    acc[mi][ni] = __builtin_amdgcn_mfma_f32_16x16x32_f16(
                        af[mi], bf[ni], acc[mi][ni], 0, 0, 0);
        }

        if (kt < GK / 64 - 1) {
            __syncthreads();
            int k0 = (kt + 1) * 64;
            stage(Xf, Af, m0, k0);
            stage(WfT, Bf, n0, k0);
        }
    }

    // ---- epilogue: +bias; q/k: fused RoPE (fast sincos) then bf16 once;
    // v: transposed store ----
#pragma unroll
    for (int ni = 0; ni < 4; ++ni) {
        int n = n0 + wn + ni * 16 + l16;
        float bv = bias[n];
        if (n < 2 * DIM) {
            float scale = (n < DIM) ? QSCALE : 1.0f;
            bool doRope = ((n & 63) < 32);        // uniform per ni
            float invf = 0.f;
            if (doRope) {
                int pair = (n & 31) >> 1;
                invf = exp2f(-(float)pair * (13.287712379549449f / 16.0f)) * INV2PI;
            }
#pragma unroll
            for (int mi = 0; mi < 4; ++mi) {
                int m = m0 + wm + mi * 16 + quad * 4;
#pragma unroll
                for (int r = 0; r < 4; ++r) {
                    float v = acc[mi][ni][r] + bv;
                    float o = v;
                    if (doRope) {
                        float partner = __shfl_xor(v, 1, 64);  // n^1 in lane l16^1
                        int token = (m + r) & (SEQ - 1);
                        float rev = (float)token * invf;
                        rev -= floorf(rev);
                        float ang = rev * TWOPI;
                        float s = __sinf(ang), c = __cosf(ang);
                        o = (n & 1) ? (v * c + partner * s) : (v * c - partner * s);
                    }
                    qkB[(size_t)(m + r) * QKP + n] = f2bf(o * scale);
                }
            }
        } else {
            int d  = n & 63;
            int hh = (n - 2 * DIM) >> 6;
#pragma unroll
            for (int mi = 0; mi < 4; ++mi) {
                int m = m0 + wm + mi * 16 + quad * 4;
                int bhh = (m >> 11) * 16 + hh;
                ushort4 pkv;
                pkv.x = f2bf(acc[mi][ni][0] + bv);
                pkv.y = f2bf(acc[mi][ni][1] + bv);
                pkv.z = f2bf(acc[mi][ni][2] + bv);
                pkv.w = f2bf(acc[mi][ni][3] + bv);
                *reinterpret_cast<ushort4*>(
                    &VTo[((size_t)bhh * HD + d) * SEQ + (m & (SEQ - 1))]) = pkv;
            }
        }
    }
}

// ---------------------------------------------------------------------------
// Kernel 3: MFMA flash attention (unchanged from R9): S^T form, 256-query
// blocks, double-buffered K/V LDS, one barrier per 128-key tile, XCD swizzle,
// key-permuted K staging, ones-row MFMA for the softmax denominator.
// ---------------------------------------------------------------------------
__global__ __launch_bounds__(256, 2) void attn_mfma4(const unsigned short* __restrict__ qkB,
                                                     const unsigned short* __restrict__ VT,
                                                     float* __restrict__ out)
{
    __shared__ __align__(16) unsigned short Ks[2][128 * 64];
    __shared__ __align__(16) unsigned short Vt[2][64 * 128];

    const int tid  = threadIdx.x;
    const int w    = tid >> 6;
    const int lane = tid & 63;
    const int quad = lane >> 4;
    const int l16  = lane & 15;
    const int bh  = blockIdx.x;       // 64  -> XCD = bh % 8
    const int qtb = blockIdx.y;       // 8
    const int bi = bh >> 4, h = bh & 15;
    const int m0 = qtb * 256 + w * 64;   // this wave's first query

    const unsigned short* Qg  = qkB + (size_t)bi * SEQ * QKP + h * HD;
    const unsigned short* Kg  = Qg + DIM;
    const unsigned short* VTg = VT + (size_t)bh * HD * SEQ;

    bf16x8 qf[4][2];
#pragma unroll
    for (int qt = 0; qt < 4; ++qt)
#pragma unroll
        for (int ks = 0; ks < 2; ++ks)
            qf[qt][ks] = *reinterpret_cast<const bf16x8*>(
                &Qg[(size_t)(m0 + qt * 16 + l16) * QKP + ks * 32 + quad * 8]);

    auto stageKV = [&](int b, int c0) {
#pragma unroll
        for (int p = 0; p < 4; ++p) {
            int seg = p * 4 + w;
            int r = seg * 8 + (lane >> 3);
            int a = (r & ~31) | (((r >> 2) & 3) << 3)
                  | (((r >> 4) & 1) << 2) | (r & 3);
            int s = (lane & 7) ^ (r & 7);
            gl_lds16(Kg + (size_t)(c0 + a) * QKP + s * 8, &Ks[b][seg * 512]);
        }
#pragma unroll
        for (int p = 0; p < 4; ++p) {
            int seg = p * 4 + w;
            int r = seg * 4 + (lane >> 4);
            int s = (lane & 15) ^ (r & 15);
            gl_lds16(VTg + (size_t)r * SEQ + c0 + s * 8, &Vt[b][seg * 512]);
        }
    };

    const u32 onepair = (l16 == 0) ? 0x3F803F80u : 0u;
    const bf16x8 ones_a = __builtin_bit_cast(
        bf16x8, (u32x4){onepair, onepair, onepair, onepair});

    f32x4 y[4][4];
#pragma unroll
    for (int qt = 0; qt < 4; ++qt)
#pragma unroll
        for (int dt = 0; dt < 4; ++dt) y[qt][dt] = (f32x4){0.f, 0.f, 0.f, 0.f};
    f32x4 yl[4];
#pragma unroll
    for (int qt = 0; qt < 4; ++qt) yl[qt] = (f32x4){0.f, 0.f, 0.f, 0.f};

    stageKV(0, 0);

    for (int t = 0; t < SEQ / 128; ++t) {
        __syncthreads();
        const int b = t & 1;
        if (t < SEQ / 128 - 1) stageKV(b ^ 1, (t + 1) * 128);

        const unsigned short* Kb = Ks[b];
        const unsigned short* Vb = Vt[b];

#pragma unroll
        for (int ksp = 0; ksp < 4; ++ksp) {
            u32 pk[4][2][2];
#pragma unroll
            for (int t2 = 0; t2 < 2; ++t2) {
                int kt = ksp * 2 + t2;
                int krow = (kt * 16 + l16) * 64;
                bf16x8 kb0 = *reinterpret_cast<const bf16x8*>(
                    &Kb[krow + ((quad ^ (l16 & 7))) * 8]);
                bf16x8 kb1 = *reinterpret_cast<const bf16x8*>(
                    &Kb[krow + (((4 + quad) ^ (l16 & 7))) * 8]);
#pragma unroll
                for (int qt = 0; qt < 4; ++qt) {
                    f32x4 st = __builtin_amdgcn_mfma_f32_16x16x32_bf16(
                        kb0, qf[qt][0], (f32x4){0.f, 0.f, 0.f, 0.f}, 0, 0, 0);
                    st = __builtin_amdgcn_mfma_f32_16x16x32_bf16(
                        kb1, qf[qt][1], st, 0, 0, 0);
                    u32 e[4];
#pragma unroll
                    for (int r = 0; r < 4; ++r)
                        e[r] = __builtin_bit_cast(u32, EXP2(st[r]));
                    pk[qt][t2][0] = __builtin_amdgcn_perm(e[1], e[0], 0x07060302u);
                    pk[qt][t2][1] = __builtin_amdgcn_perm(e[3], e[2], 0x07060302u);
                }
            }
            bf16x8 pfragq[4];
#pragma unroll
            for (int qt = 0; qt < 4; ++qt) {
                pfragq[qt] = __builtin_bit_cast(
                    bf16x8, (u32x4){pk[qt][0][0], pk[qt][0][1], pk[qt][1][0], pk[qt][1][1]});
                yl[qt] = __builtin_amdgcn_mfma_f32_16x16x32_bf16(
                    ones_a, pfragq[qt], yl[qt], 0, 0, 0);
            }
#pragma unroll
            for (int dt = 0; dt < 4; ++dt) {
                int row = dt * 16 + l16;
                bf16x8 vfrag = *reinterpret_cast<const bf16x8*>(
                    &Vb[row * 128 + (((ksp * 4 + quad) ^ l16)) * 8]);
#pragma unroll
                for (int qt = 0; qt < 4; ++qt)
                    y[qt][dt] = __builtin_amdgcn_mfma_f32_16x16x32_bf16(
                        vfrag, pfragq[qt], y[qt][dt], 0, 0, 0);
            }
        }
    }

#pragma unroll
    for (int qt = 0; qt < 4; ++qt) {
        float lv = __shfl(yl[qt][0], l16, 64);
        float rsv = 1.f / lv;
        int token = m0 + qt * 16 + l16;
        size_t obase = ((size_t)(bi * SEQ + token)) * DIM + h * HD;
#pragma unroll
        for (int dt = 0; dt < 4; ++dt) {
            float4 o;
            o.x = y[qt][dt][0] * rsv;
            o.y = y[qt][dt][1] * rsv;
            o.z = y[qt][dt][2] * rsv;
            o.w = y[qt][dt][3] * rsv;
            *reinterpret_cast<float4*>(&out[obase + dt * 16 + quad * 4]) = o;
        }
    }
}

// ---------------------------------------------------------------------------
extern "C" void kernel_launch(void* const* d_in, const int* in_sizes, int n_in,
                              void* d_out, int out_size, void* d_ws, size_t ws_size,
                              hipStream_t stream)
{
    const float* x    = (const float*)d_in[0];
    const float* W    = (const float*)d_in[1];
    const float* bias = (const float*)d_in[2];
    float* out = (float*)d_out;

    // ws layout (ushort elems): qkB 32MB | VT 16MB | Xf 16MB | WfT 6MB = 70MB
    unsigned short* qkB = (unsigned short*)d_ws;                  // 8192*2048
    unsigned short* VT  = qkB + (size_t)MROWS * QKP;              // 64*64*2048
    unsigned short* Xf  = VT + (size_t)BATCH * NHEAD * HD * SEQ;  // 8192*1024
    unsigned short* WfT = Xf + (size_t)MROWS * GK;                // 3072*1024

    prep<<<4096 + 3072, 256, 0, stream>>>(x, W, Xf, WfT);
    gemm_f16<<<dim3(NQKV / 128, MROWS / 128), 256, 0, stream>>>(Xf, WfT, bias, qkB, VT);
    attn_mfma4<<<dim3(BATCH * NHEAD, SEQ / 256), 256, 0, stream>>>(qkB, VT, out);
}